// Round 1
// baseline (635.873 us; speedup 1.0000x reference)
//
#include <hip/hip_runtime.h>

// Problem constants (X, Y: (64, 128, 64) fp32)
#define AA   64      // batch size
#define MM   128     // path length
#define DD   64      // feature dim
#define M1   127     // rows/cols of inc grid (MM-1)
#define TILE 32      // dX rows per LDS tile
#define WPB  4       // waves (pairs) per block

// ---------------------------------------------------------------------------
// init kernel: out[0] = mean((X[:,0,:] - Y[:,0,:])^2)   (also zero-inits the
// accumulator that the PDE blocks atomicAdd into — d_out is poisoned 0xAA
// before every launch)
// ---------------------------------------------------------------------------
__global__ void init_out(const float* __restrict__ X, const float* __restrict__ Y,
                         float* __restrict__ out) {
    __shared__ float red[4];
    int tid = threadIdx.x;                    // 256 threads
    float acc = 0.f;
    for (int e = tid; e < AA * DD; e += 256) {
        int aa = e >> 6, d = e & 63;
        float df = X[aa * (MM * DD) + d] - Y[aa * (MM * DD) + d];
        acc = fmaf(df, df, acc);
    }
    #pragma unroll
    for (int off = 32; off > 0; off >>= 1) acc += __shfl_down(acc, off);
    if ((tid & 63) == 0) red[tid >> 6] = acc;
    __syncthreads();
    if (tid == 0) {
        float s = red[0] + red[1] + red[2] + red[3];
        out[0] = s / (float)(AA * DD);
    }
}

// ---------------------------------------------------------------------------
// PDE kernel: one wave per (a,b) pair; 4 pairs (same a) per block share the
// dX LDS tile. Lane l owns columns 2l, 2l+1 of the K row.
//   delta[j] = K[j+1] - K[j] + K[j]*inc[i][j]
//   K_new    = [1, 1 + cumsum(delta)]
// ---------------------------------------------------------------------------
__global__ __launch_bounds__(256, 3)
void sig_pde_kernel(const float* __restrict__ X, const float* __restrict__ Y,
                    float* __restrict__ out) {
    const int tid  = threadIdx.x;
    const int lane = tid & 63;
    const int w    = tid >> 6;

    const int BPG = AA * (AA / WPB);          // 1024 blocks per gram
    int gid = blockIdx.x;
    const int g   = gid / BPG;                // 0: XX, 1: YY, 2: XY
    int rem = gid - g * BPG;
    const int a   = rem / (AA / WPB);
    const int bq  = rem - a * (AA / WPB);
    const int b   = bq * WPB + w;

    const float* P = (g == 1) ? Y : X;        // rows (i direction)
    const float* Q = (g == 0) ? X : Y;        // cols (j direction)
    const float wgt = (g == 2) ? (-2.0f / 4096.0f) : (1.0f / 4096.0f);

    __shared__ float dXs[2][TILE][DD];        // 16 KB, double-buffered

    // --- load this wave's two dY columns into registers -------------------
    const int j0 = 2 * lane;                          // 0..126
    const int j1 = (j0 + 1 < M1) ? (j0 + 1) : (M1 - 1); // clamp lane 63 (unused)
    float dy0[DD], dy1[DD];
    const float* Qb = Q + b * (MM * DD);
    #pragma unroll
    for (int dd = 0; dd < DD / 4; ++dd) {
        float4 r0 = *(const float4*)(Qb + j0 * DD + 4 * dd);
        float4 r1 = *(const float4*)(Qb + (j0 + 1) * DD + 4 * dd);
        float4 rb = *(const float4*)(Qb + j1 * DD + 4 * dd);
        float4 r2 = *(const float4*)(Qb + (j1 + 1) * DD + 4 * dd);
        dy0[4*dd+0] = r1.x - r0.x;  dy0[4*dd+1] = r1.y - r0.y;
        dy0[4*dd+2] = r1.z - r0.z;  dy0[4*dd+3] = r1.w - r0.w;
        dy1[4*dd+0] = r2.x - rb.x;  dy1[4*dd+1] = r2.y - rb.y;
        dy1[4*dd+2] = r2.z - rb.z;  dy1[4*dd+3] = r2.w - rb.w;
    }

    // --- cooperative dX tile staging --------------------------------------
    const float* Pa = P + a * (MM * DD);
    auto stage = [&](int t0, int buf) {
        // TILE*DD = 2048 floats = 512 float4; 256 threads -> 2 each
        #pragma unroll
        for (int e = 0; e < 2; ++e) {
            int idx = e * 256 + tid;          // 0..511
            int i   = idx >> 4;               // row within tile
            int c   = idx & 15;               // float4 chunk
            int row = t0 + i;
            if (row < M1) {
                float4 lo = *(const float4*)(Pa + row * DD + 4 * c);
                float4 hi = *(const float4*)(Pa + (row + 1) * DD + 4 * c);
                float4 d4;
                d4.x = hi.x - lo.x; d4.y = hi.y - lo.y;
                d4.z = hi.z - lo.z; d4.w = hi.w - lo.w;
                *(float4*)(&dXs[buf][i][4 * c]) = d4;
            }
        }
    };

    float k0 = 1.0f, k1 = 1.0f;               // K[2l], K[2l+1] of current row
    int buf = 0;
    stage(0, 0);
    __syncthreads();

    for (int t0 = 0; t0 < M1; t0 += TILE) {
        if (t0 + TILE < M1) stage(t0 + TILE, buf ^ 1);
        const int rows = (M1 - t0 < TILE) ? (M1 - t0) : TILE;
        for (int ii = 0; ii < rows; ++ii) {
            const float* xr = &dXs[buf][ii][0];
            float s0 = 0.f, s1 = 0.f;
            #pragma unroll
            for (int d = 0; d < DD; ++d) {
                float xd = xr[d];
                s0 = fmaf(xd, dy0[d], s0);
                s1 = fmaf(xd, dy1[d], s1);
            }
            // delta pair for this lane
            float kp2 = __shfl_down(k0, 1);                    // K[2l+2]
            float e0  = k1 - k0 + k0 * s0;                     // delta[2l]
            float e1  = (lane < 63) ? (kp2 - k1 + k1 * s1) : 0.0f; // delta[2l+1]
            float t   = e0 + e1;
            // 64-lane inclusive scan of t
            float S = t;
            #pragma unroll
            for (int off = 1; off < 64; off <<= 1) {
                float n = __shfl_up(S, off);
                S += (lane >= off) ? n : 0.0f;
            }
            float Sp = __shfl_up(S, 1);                        // S_{l-1}
            k0 = (lane == 0) ? 1.0f : 1.0f + Sp;               // K_new[2l]
            k1 = 1.0f + S - e1;                                // K_new[2l+1]
        }
        __syncthreads();
        buf ^= 1;
    }

    // lane 63's k1 == K[127][127] for this pair
    if (lane == 63) atomicAdd(out, wgt * k1);
}

extern "C" void kernel_launch(void* const* d_in, const int* in_sizes, int n_in,
                              void* d_out, int out_size, void* d_ws, size_t ws_size,
                              hipStream_t stream) {
    const float* X = (const float*)d_in[0];
    const float* Y = (const float*)d_in[1];
    float* out = (float*)d_out;

    hipLaunchKernelGGL(init_out, dim3(1), dim3(256), 0, stream, X, Y, out);

    const int blocks = 3 * AA * (AA / WPB);   // 3072
    hipLaunchKernelGGL(sig_pde_kernel, dim3(blocks), dim3(256), 0, stream,
                       X, Y, out);
}